// Round 4
// baseline (667.541 us; speedup 1.0000x reference)
//
#include <hip/hip_runtime.h>

typedef __bf16 bf16_t;
typedef __bf16 bf16x8 __attribute__((ext_vector_type(8)));
typedef float f32x4 __attribute__((ext_vector_type(4)));

__device__ inline bf16x8 zero8v() {
  bf16x8 v;
#pragma unroll
  for (int i = 0; i < 8; ++i) v[i] = (__bf16)0.0f;
  return v;
}

// async global->LDS, 16B per lane, wave-uniform LDS base + lane*16
__device__ inline void gl_lds16(const bf16_t* g, bf16_t* l) {
  __builtin_amdgcn_global_load_lds(
      (const __attribute__((address_space(1))) void*)g,
      (__attribute__((address_space(3))) void*)l, 16, 0, 0);
}

// ---------------- fp32 NCHW -> bf16 NHWC (LDS tile transpose) ----------------
__global__ __launch_bounds__(256)
void nchw_to_nhwc(const float* __restrict__ in, bf16_t* __restrict__ out,
                  int C, int HW) {
  __shared__ float tile[64][65];
  const int n = blockIdx.z;
  const int c0 = blockIdx.y * 64, p0 = blockIdx.x * 64;
  const int t = threadIdx.x;
  const float* src = in + ((size_t)n * C + c0) * HW + p0;
  const int cl = t >> 6;
  const int pl = t & 63;
#pragma unroll
  for (int i = 0; i < 16; ++i)
    tile[cl + i * 4][pl] = src[(size_t)(cl + i * 4) * HW + pl];
  __syncthreads();
  bf16_t* dst = out + ((size_t)n * HW + p0) * C + c0;
  const int pc = t >> 6;
  const int cc = t & 63;
#pragma unroll
  for (int i = 0; i < 16; ++i)
    dst[(size_t)(pc + i * 4) * C + cc] = (bf16_t)tile[cc][pc + i * 4];
}

// ---------------- all weight transforms in one kernel ------------------------
struct WSrc {
  const float *lw0, *lw1, *lw2;
  const float* w9[9];   // fw0,fw1,fw2,cw0,cw1,cw2,rw0,rw1,rw2
  int O9[9];            // 256,256,256,256,256,240,256,256,12
};
__global__ __launch_bounds__(256)
void weight_prep(WSrc s, bf16_t* __restrict__ LWT0, bf16_t* __restrict__ LWT1,
                 bf16_t* __restrict__ LWT2, bf16_t* __restrict__ W33) {
  int idx = blockIdx.x * 256 + threadIdx.x;
  if (idx < 131072) { LWT0[idx] = (bf16_t)s.lw0[idx]; return; }
  if (idx < 393216) { int i = idx - 131072; LWT1[i] = (bf16_t)s.lw1[i]; return; }
  if (idx < 917504) { int i = idx - 393216; LWT2[i] = (bf16_t)s.lw2[i]; return; }
  int t2 = idx - 917504;
  if (t2 >= 9 * 589824) return;
  int sgi = t2 / 589824;
  int r = t2 - sgi * 589824;
  int kid = r >> 16;            // 9 taps * 65536
  int rem = r & 65535;
  int o = rem >> 8, ci = rem & 255;
  const float* src = s.w9[sgi];
  int O = s.O9[sgi];
  W33[t2] = (o < O) ? (bf16_t)src[((size_t)o * 256 + ci) * 9 + kid] : (bf16_t)0.0f;
}

// ---------------- halo zeroing of padded NHWC buffers ------------------------
struct HZPack { bf16_t* base[6]; int cnt8[6]; int Wp[6]; int Hp[6]; int ns[6]; };
__global__ __launch_bounds__(256)
void halo_zero(HZPack h) {
  int gid = blockIdx.x * 256 + threadIdx.x;
  int bi = 0;
#pragma unroll 1
  for (; bi < 5; ++bi) {
    if (gid < h.cnt8[bi]) break;
    gid -= h.cnt8[bi];
  }
  if (gid >= h.cnt8[bi]) return;
  const int Wp = h.Wp[bi], Hp = h.Hp[bi];
  const int c8 = gid & 31;
  const int rest = gid >> 5;
  const int perim = 2 * Wp + 2 * (Hp - 2);
  const int img = rest / perim;
  const int p = rest - img * perim;
  int y, x;
  if (p < Wp)            { y = 0;       x = p; }
  else if (p < 2 * Wp)   { y = Hp - 1;  x = p - Wp; }
  else { int q = p - 2 * Wp; y = 1 + (q >> 1); x = (q & 1) ? (Wp - 1) : 0; }
  bf16_t* d = h.base[bi] + ((size_t)img * h.ns[bi] + y * Wp + x) * 256 + c8 * 8;
  *(bf16x8*)d = zero8v();
}

// ---------------- dst(padded NHWC) += up2(src(padded NHWC)), C == 256 --------
__global__ __launch_bounds__(256)
void up2_add_p(bf16_t* __restrict__ dst, const bf16_t* __restrict__ src,
               int lw, int lhw, int dWp, int dNs, int sWp, int sNs, int tot8) {
  int idx = blockIdx.x * 256 + threadIdx.x;
  if (idx >= tot8) return;
  const int c8 = idx & 31;
  const int pos = idx >> 5;
  const int n = pos >> lhw;
  const int rem = pos & ((1 << lhw) - 1);
  const int y = rem >> lw, x = rem & ((1 << lw) - 1);
  bf16_t* d = dst + ((size_t)n * dNs + (y + 1) * dWp + (x + 1)) * 256 + c8 * 8;
  const bf16_t* sp = src + ((size_t)n * sNs + ((y >> 1) + 1) * sWp + ((x >> 1) + 1)) * 256 + c8 * 8;
  bf16x8 dv = *(bf16x8*)d;
  bf16x8 sv = *(const bf16x8*)sp;
#pragma unroll
  for (int k = 0; k < 8; ++k) dv[k] = (bf16_t)((float)dv[k] + (float)sv[k]);
  *(bf16x8*)d = dv;
}

// ---------------- 1x1 conv (laterals), bf16 MFMA, global_load_lds ------------
struct Job1 {
  const bf16_t* A;    // unpadded NHWC
  const bf16_t* Wt;   // [256][Cin]
  const float* bias;
  bf16_t* outb;       // padded NHWC out
  int mtiles, lw, lhw, oWp, onstride, Cin, pad0, pad1;
};
struct Job1Pack { Job1 j[3]; };

__global__ __launch_bounds__(256, 2)
void conv1_batch(Job1Pack jp) {
  __shared__ __align__(16) bf16_t As[128 * 32];
  __shared__ __align__(16) bf16_t Bs[128 * 32];
  int b = blockIdx.x, ji = 0;
#pragma unroll 1
  for (; ji < 2; ++ji) {
    int sz = jp.j[ji].mtiles * 2;
    if (b < sz) break;
    b -= sz;
  }
  const Job1 J = jp.j[ji];
  const int nt = b & 1, mt = b >> 1;
  const int m0 = mt * 128, n0 = nt * 128;
  const int t = threadIdx.x, l = t & 63, w = t >> 6;
  const int W = 1 << J.lw, HW = 1 << J.lhw;
  const int sr = l >> 2, seg = (l & 3) * 8;
  const bf16_t* aptr[2];
  const bf16_t* bptr[2];
  bf16_t* alds[2];
  bf16_t* blds[2];
#pragma unroll
  for (int q = 0; q < 2; ++q) {
    const int r = w * 32 + q * 16 + sr;
    aptr[q] = J.A + (size_t)(m0 + r) * J.Cin + seg;
    alds[q] = &As[(w * 32 + q * 16) * 32];
    bptr[q] = J.Wt + (size_t)(n0 + r) * J.Cin + seg;
    blds[q] = &Bs[(w * 32 + q * 16) * 32];
  }
  const int fr = l & 15, qd = l >> 4;
  const int wm = (w & 1) * 64, wn = (w >> 1) * 64;

  f32x4 acc[4][4];
#pragma unroll
  for (int i = 0; i < 4; ++i)
#pragma unroll
    for (int j = 0; j < 4; ++j)
#pragma unroll
      for (int r = 0; r < 4; ++r) acc[i][j][r] = 0.0f;

  const int kiters = J.Cin >> 5;
#pragma unroll 1
  for (int kk = 0; kk < kiters; ++kk) {
    __syncthreads();
    gl_lds16(aptr[0], alds[0]);
    gl_lds16(aptr[1], alds[1]);
    gl_lds16(bptr[0], blds[0]);
    gl_lds16(bptr[1], blds[1]);
    __syncthreads();
    aptr[0] += 32; aptr[1] += 32; bptr[0] += 32; bptr[1] += 32;
    bf16x8 af[4], bfv[4];
#pragma unroll
    for (int i = 0; i < 4; ++i)
      af[i] = *(const bf16x8*)&As[(wm + i * 16 + fr) * 32 + qd * 8];
#pragma unroll
    for (int j = 0; j < 4; ++j)
      bfv[j] = *(const bf16x8*)&Bs[(wn + j * 16 + fr) * 32 + qd * 8];
#pragma unroll
    for (int i = 0; i < 4; ++i)
#pragma unroll
      for (int j = 0; j < 4; ++j)
        acc[i][j] = __builtin_amdgcn_mfma_f32_16x16x32_bf16(af[i], bfv[j],
                                                            acc[i][j], 0, 0, 0);
  }

#pragma unroll
  for (int i = 0; i < 4; ++i) {
    const int mrow = m0 + wm + i * 16 + qd * 4;
#pragma unroll
    for (int j = 0; j < 4; ++j) {
      const int co = n0 + wn + j * 16 + fr;
      const float bv = J.bias[co];
#pragma unroll
      for (int r = 0; r < 4; ++r) {
        float v = acc[i][j][r] + bv;
        const int m = mrow + r;
        const int n = m >> J.lhw, hw = m & (HW - 1);
        const int y = hw >> J.lw, x = hw & (W - 1);
        J.outb[((size_t)n * J.onstride + (y + 1) * J.oWp + (x + 1)) * 256 + co] =
            (bf16_t)v;
      }
    }
  }
}

// ------- 3x3 conv, 256m x 128n block, wave tile 128x64 (acc 8x4), Cin==256 ---
struct Job3 {
  const bf16_t* A;    // padded NHWC (halo zeros), pitch Wp, per-image nsA px
  const bf16_t* Wt;   // [9][256][256]
  const float* bias;
  bf16_t* outb;       // padded NHWC out (or null -> outf)
  int mtiles, ntiles, lw, lhw, Wp, nsA, oWp, onstride;
  int relu, Cout, pos_off, ch_off, use_outf, nAr, Pc, pad_;
};
struct Job3Pack { Job3 j[6]; };

__global__ __launch_bounds__(256, 2)
void conv3_batch(Job3Pack jp, float* __restrict__ outf) {
  __shared__ __align__(16) bf16_t As[448 * 32];   // up to 448 padded px, 32 ch
  __shared__ __align__(16) bf16_t Bs[384 * 32];   // 3 taps x 128 co x 32 ci
  int b = blockIdx.x, ji = 0;
#pragma unroll 1
  for (; ji < 5; ++ji) {
    int sz = jp.j[ji].mtiles * jp.j[ji].ntiles;
    if (b < sz) break;
    b -= sz;
  }
  const Job3 J = jp.j[ji];
  const int nt = (J.ntiles == 2) ? (b & 1) : 0;
  const int mt = (J.ntiles == 2) ? (b >> 1) : b;
  const int m0 = mt * 256, n0 = nt * 128;
  const int t = threadIdx.x, l = t & 63, w = t >> 6;
  const int W = 1 << J.lw, HW = 1 << J.lhw;
  const int sr = l >> 2, seg = (l & 3) * 8;
  const int fr = l & 15, qd = l >> 4;
  const int wm = (w & 1) * 128, wn = (w >> 1) * 64;

  const int n_img = m0 >> J.lhw;
  const int Y0 = (m0 & (HW - 1)) >> J.lw;
  const bf16_t* Ag = J.A + ((size_t)n_img * J.nsA + (size_t)Y0 * J.Wp) * 256 + seg;

  // B staging: 6 rounds cover 3 taps x 128 rows of 32ch
  const bf16_t* bp[6];
  bf16_t* blds[6];
#pragma unroll
  for (int r = 0; r < 6; ++r) {
    const int R_ = r * 64 + w * 16 + sr;
    const int tp = R_ >> 7, co = R_ & 127;
    bp[r] = J.Wt + ((size_t)tp * 256 + n0 + co) * 256 + seg;
    blds[r] = &Bs[(r * 64 + w * 16) * 32];
  }
  // A staging: nAr rounds cover Pc padded pixels of 32ch
  const bf16_t* ap[7];
  bf16_t* aldsv[7];
#pragma unroll
  for (int r = 0; r < 7; ++r) {
    int p = r * 64 + w * 16 + sr;
    if (p > J.Pc - 1) p = J.Pc - 1;
    ap[r] = Ag + (size_t)p * 256;
    aldsv[r] = &As[(r * 64 + w * 16) * 32];
  }
  int apix[8];
#pragma unroll
  for (int i = 0; i < 8; ++i) {
    const int m = wm + i * 16 + fr;
    const int y = m >> J.lw, x = m & (W - 1);
    apix[i] = ((y + 1) * J.Wp + (x + 1)) * 32 + qd * 8;
  }

  f32x4 acc[8][4];
#pragma unroll
  for (int i = 0; i < 8; ++i)
#pragma unroll
    for (int j = 0; j < 4; ++j)
#pragma unroll
      for (int r = 0; r < 4; ++r) acc[i][j][r] = 0.0f;

  const int nAr = J.nAr;
#pragma unroll 1
  for (int cb = 0; cb < 8; ++cb) {
    const int cboff = cb * 32;
#pragma unroll 1
    for (int ky = 0; ky < 3; ++ky) {
      __syncthreads();
      const size_t koff = (size_t)(ky * 3) * 65536 + cboff;
#pragma unroll
      for (int r = 0; r < 6; ++r) gl_lds16(bp[r] + koff, blds[r]);
      if (ky == 0) {
#pragma unroll 1
        for (int r = 0; r < nAr; ++r) gl_lds16(ap[r] + cboff, aldsv[r]);
      }
      __syncthreads();
      const int dy = (ky - 1) * J.Wp * 32;
#pragma unroll
      for (int kx = 0; kx < 3; ++kx) {
        const int d = dy + (kx - 1) * 32;
        bf16x8 af[8], bfv[4];
#pragma unroll
        for (int i = 0; i < 8; ++i)
          af[i] = *(const bf16x8*)&As[apix[i] + d];
#pragma unroll
        for (int j = 0; j < 4; ++j)
          bfv[j] = *(const bf16x8*)&Bs[(kx * 128 + wn + j * 16 + fr) * 32 + qd * 8];
#pragma unroll
        for (int i = 0; i < 8; ++i)
#pragma unroll
          for (int j = 0; j < 4; ++j)
            acc[i][j] = __builtin_amdgcn_mfma_f32_16x16x32_bf16(af[i], bfv[j],
                                                                acc[i][j], 0, 0, 0);
      }
    }
  }

  // epilogue: D layout col=lane&15, row=(lane>>4)*4+reg
#pragma unroll
  for (int i = 0; i < 8; ++i) {
    const int mrow = m0 + wm + i * 16 + qd * 4;
#pragma unroll
    for (int j = 0; j < 4; ++j) {
      const int co = n0 + wn + j * 16 + fr;
      if (co < J.Cout) {
        const float bv = J.bias[co];
#pragma unroll
        for (int r = 0; r < 4; ++r) {
          float v = acc[i][j][r] + bv;
          if (J.relu) v = fmaxf(v, 0.0f);
          const int m = mrow + r;
          const int n = m >> J.lhw, hw = m & (HW - 1);
          if (J.use_outf) {
            outf[((size_t)n * 5376 + J.pos_off + hw) * 252 + J.ch_off + co] = v;
          } else {
            const int y = hw >> J.lw, x = hw & (W - 1);
            J.outb[((size_t)n * J.onstride + (y + 1) * J.oWp + (x + 1)) * 256 + co] =
                (bf16_t)v;
          }
        }
      }
    }
  }
}

// ---------------- anchors ----------------------------------------------------
__global__ __launch_bounds__(256)
void anchors_k(float* __restrict__ out) {
  int r = blockIdx.x * 256 + threadIdx.x;
  if (r >= 16128) return;
  int local, w, stride;
  float bs;
  if (r < 12288)      { local = r;          w = 64; stride = 8;  bs = 32.f;  }
  else if (r < 15360) { local = r - 12288;  w = 32; stride = 16; bs = 64.f;  }
  else                { local = r - 15360;  w = 16; stride = 32; bs = 128.f; }
  const int a = local % 3;
  const int s = local / 3;
  const int y = s / w, x = s - y * w;
  const float ar = (a == 0) ? 0.5f : (a == 1) ? 1.0f : 2.0f;
  const float sq = sqrtf(ar);
  const float hw_ = bs * sq * 0.5f, hh = bs / sq * 0.5f;
  const float cx = (float)x * (float)stride, cy = (float)y * (float)stride;
  out[(size_t)r * 4 + 0] = cx - hw_;
  out[(size_t)r * 4 + 1] = cy - hh;
  out[(size_t)r * 4 + 2] = cx + hw_;
  out[(size_t)r * 4 + 3] = cy + hh;
}

// ---------------- launch -----------------------------------------------------
extern "C" void kernel_launch(void* const* d_in, const int* in_sizes, int n_in,
                              void* d_out, int out_size, void* d_ws, size_t ws_size,
                              hipStream_t stream) {
  const float* feat3 = (const float*)d_in[0];
  const float* feat4 = (const float*)d_in[1];
  const float* feat5 = (const float*)d_in[2];
  const float* lw0 = (const float*)d_in[3];  const float* lb0 = (const float*)d_in[4];
  const float* lw1 = (const float*)d_in[5];  const float* lb1 = (const float*)d_in[6];
  const float* lw2 = (const float*)d_in[7];  const float* lb2 = (const float*)d_in[8];
  const float* fw0 = (const float*)d_in[9];  const float* fb0 = (const float*)d_in[10];
  const float* fw1 = (const float*)d_in[11]; const float* fb1 = (const float*)d_in[12];
  const float* fw2 = (const float*)d_in[13]; const float* fb2 = (const float*)d_in[14];
  const float* cw0 = (const float*)d_in[15]; const float* cb0 = (const float*)d_in[16];
  const float* cw1 = (const float*)d_in[17]; const float* cb1 = (const float*)d_in[18];
  const float* cw2 = (const float*)d_in[19]; const float* cb2 = (const float*)d_in[20];
  const float* rw0 = (const float*)d_in[21]; const float* rb0 = (const float*)d_in[22];
  const float* rw1 = (const float*)d_in[23]; const float* rb1 = (const float*)d_in[24];
  const float* rw2 = (const float*)d_in[25]; const float* rb2 = (const float*)d_in[26];

  char* ws = (char*)d_ws;
  float* out = (float*)d_out;

  // ---- workspace layout (bytes) ----
  bf16_t* XS3 = (bf16_t*)(ws + 0);            // 33,554,432
  bf16_t* XS4 = (bf16_t*)(ws + 33554432);     // 16,777,216
  bf16_t* XS5 = (bf16_t*)(ws + 50331648);     //  8,388,608
  bf16_t* Lp0 = (bf16_t*)(ws + 58720256);     // 8*66*66*256*2 = 17,842,176
  bf16_t* Lp1 = (bf16_t*)(ws + 76562432);     // 8*34*34*256*2 =  4,734,976
  bf16_t* Lp2 = (bf16_t*)(ws + 81297408);     // 8*18*18*256*2 =  1,327,104
  bf16_t* Pp0 = (bf16_t*)(ws + 82624512);     // 17,842,176
  bf16_t* Pp1 = (bf16_t*)(ws + 100466688);    //  4,734,976
  bf16_t* Pp2 = (bf16_t*)(ws + 105201664);    //  1,327,104
  bf16_t* LWT0 = (bf16_t*)(ws + 106528768);   //    262,144
  bf16_t* LWT1 = (bf16_t*)(ws + 106790912);   //    524,288
  bf16_t* LWT2 = (bf16_t*)(ws + 107315200);   //  1,048,576
  bf16_t* W33  = (bf16_t*)(ws + 108363776);   // 9 * 1,179,648
  bf16_t* FWT0 = W33 + 0 * 589824;
  bf16_t* FWT1 = W33 + 1 * 589824;
  bf16_t* FWT2 = W33 + 2 * 589824;
  bf16_t* CWT0 = W33 + 3 * 589824;
  bf16_t* CWT1 = W33 + 4 * 589824;
  bf16_t* CWT2 = W33 + 5 * 589824;
  bf16_t* RWT0 = W33 + 6 * 589824;
  bf16_t* RWT1 = W33 + 7 * 589824;
  bf16_t* RWT2 = W33 + 8 * 589824;
  // T region: aliases XS3+XS4 (dead after laterals)
  bf16_t* TAc0 = (bf16_t*)(ws + 0);
  bf16_t* TAr0 = (bf16_t*)(ws + 17842176);
  bf16_t* TAc1 = (bf16_t*)(ws + 35684352);
  bf16_t* TAr1 = (bf16_t*)(ws + 40419328);
  bf16_t* TAc2 = (bf16_t*)(ws + 45154304);
  bf16_t* TAr2 = (bf16_t*)(ws + 46481408);    // end 47,808,512
  bf16_t* TBc0 = Pp0; bf16_t* TBr0 = Lp0;
  bf16_t* TBc1 = Pp1; bf16_t* TBr1 = Lp1;
  bf16_t* TBc2 = Pp2; bf16_t* TBr2 = Lp2;

  // 1. weight prep
  WSrc wsrc;
  wsrc.lw0 = lw0; wsrc.lw1 = lw1; wsrc.lw2 = lw2;
  const float* w9s[9] = {fw0, fw1, fw2, cw0, cw1, cw2, rw0, rw1, rw2};
  int o9s[9] = {256, 256, 256, 256, 256, 240, 256, 256, 12};
  for (int i = 0; i < 9; ++i) { wsrc.w9[i] = w9s[i]; wsrc.O9[i] = o9s[i]; }
  weight_prep<<<dim3(24320), 256, 0, stream>>>(wsrc, LWT0, LWT1, LWT2, W33);

  // 2. activation casts to NHWC bf16
  nchw_to_nhwc<<<dim3(64, 8, 8),  256, 0, stream>>>(feat3, XS3, 512, 4096);
  nchw_to_nhwc<<<dim3(16, 16, 8), 256, 0, stream>>>(feat4, XS4, 1024, 1024);
  nchw_to_nhwc<<<dim3(4, 32, 8),  256, 0, stream>>>(feat5, XS5, 2048, 256);

  // 3. halo zeros for Lp/Pp (interiors fully written by convs)
  {
    HZPack h;
    bf16_t* bs[6] = {Lp0, Pp0, Lp1, Pp1, Lp2, Pp2};
    int cnt[6] = {66560, 66560, 33792, 33792, 17408, 17408};
    int wp[6] = {66, 66, 34, 34, 18, 18};
    int hp[6] = {66, 66, 34, 34, 18, 18};
    int ns[6] = {4356, 4356, 1156, 1156, 324, 324};
    for (int i = 0; i < 6; ++i) { h.base[i]=bs[i]; h.cnt8[i]=cnt[i]; h.Wp[i]=wp[i]; h.Hp[i]=hp[i]; h.ns[i]=ns[i]; }
    halo_zero<<<dim3(920), 256, 0, stream>>>(h);
  }

  // 4. lateral 1x1 convs
  {
    Job1Pack jp;
    jp.j[0] = {XS3, LWT0, lb0, Lp0, 256, 6, 12, 66, 4356, 512, 0, 0};
    jp.j[1] = {XS4, LWT1, lb1, Lp1, 64, 5, 10, 34, 1156, 1024, 0, 0};
    jp.j[2] = {XS5, LWT2, lb2, Lp2, 16, 4, 8, 18, 324, 2048, 0, 0};
    conv1_batch<<<dim3(672), 256, 0, stream>>>(jp);
  }

  // 5. halo zeros for TA region (XS3/XS4 dead after conv1)
  {
    HZPack h;
    bf16_t* bs[6] = {TAc0, TAr0, TAc1, TAr1, TAc2, TAr2};
    int cnt[6] = {66560, 66560, 33792, 33792, 17408, 17408};
    int wp[6] = {66, 66, 34, 34, 18, 18};
    int hp[6] = {66, 66, 34, 34, 18, 18};
    int ns[6] = {4356, 4356, 1156, 1156, 324, 324};
    for (int i = 0; i < 6; ++i) { h.base[i]=bs[i]; h.cnt8[i]=cnt[i]; h.Wp[i]=wp[i]; h.Hp[i]=hp[i]; h.ns[i]=ns[i]; }
    halo_zero<<<dim3(920), 256, 0, stream>>>(h);
  }

  // 6. top-down fusion
  up2_add_p<<<dim3(1024), 256, 0, stream>>>(Lp1, Lp2, 5, 10, 34, 1156, 18, 324, 262144);
  up2_add_p<<<dim3(4096), 256, 0, stream>>>(Lp0, Lp1, 6, 12, 66, 4356, 34, 1156, 1048576);

  auto mk3 = [](const bf16_t* A, const bf16_t* Wt, const float* bias,
                bf16_t* outb, int mtiles, int ntiles, int lw, int lhw,
                int Wp, int nsA, int oWp, int onstride, int relu, int Cout,
                int pos_off, int ch_off, int use_outf, int nAr, int Pc) {
    Job3 j;
    j.A = A; j.Wt = Wt; j.bias = bias; j.outb = outb;
    j.mtiles = mtiles; j.ntiles = ntiles; j.lw = lw; j.lhw = lhw;
    j.Wp = Wp; j.nsA = nsA; j.oWp = oWp; j.onstride = onstride;
    j.relu = relu; j.Cout = Cout; j.pos_off = pos_off; j.ch_off = ch_off;
    j.use_outf = use_outf; j.nAr = nAr; j.Pc = Pc; j.pad_ = 0;
    return j;
  };
  // level geometry (256-px m-tiles):
  //  L0: lw6 lhw12 Wp66 ns4356 mt128 nAr7 Pc396
  //  L1: lw5 lhw10 Wp34 ns1156 mt32  nAr6 Pc340
  //  L2: lw4 lhw8  Wp18 ns324  mt8   nAr6 Pc324

  // 7. FPN 3x3 convs (336 blocks)
  {
    Job3Pack jp;
    jp.j[0] = mk3(Lp0, FWT0, fb0, Pp0, 128, 2, 6, 12, 66, 4356, 66, 4356, 0, 256, 0, 0, 0, 7, 396);
    jp.j[1] = mk3(Lp1, FWT1, fb1, Pp1, 32, 2, 5, 10, 34, 1156, 34, 1156, 0, 256, 0, 0, 0, 6, 340);
    jp.j[2] = mk3(Lp2, FWT2, fb2, Pp2, 8, 2, 4, 8, 18, 324, 18, 324, 0, 256, 0, 0, 0, 6, 324);
    jp.j[3] = jp.j[4] = jp.j[5] = jp.j[2];
    jp.j[3].mtiles = jp.j[4].mtiles = jp.j[5].mtiles = 0;
    conv3_batch<<<dim3(336), 256, 0, stream>>>(jp, out);
  }

  // 8. tower stage 1 (672 blocks)
  {
    Job3Pack jp;
    jp.j[0] = mk3(Pp0, CWT0, cb0, TAc0, 128, 2, 6, 12, 66, 4356, 66, 4356, 1, 256, 0, 0, 0, 7, 396);
    jp.j[1] = mk3(Pp0, RWT0, rb0, TAr0, 128, 2, 6, 12, 66, 4356, 66, 4356, 1, 256, 0, 0, 0, 7, 396);
    jp.j[2] = mk3(Pp1, CWT0, cb0, TAc1, 32, 2, 5, 10, 34, 1156, 34, 1156, 1, 256, 0, 0, 0, 6, 340);
    jp.j[3] = mk3(Pp1, RWT0, rb0, TAr1, 32, 2, 5, 10, 34, 1156, 34, 1156, 1, 256, 0, 0, 0, 6, 340);
    jp.j[4] = mk3(Pp2, CWT0, cb0, TAc2, 8, 2, 4, 8, 18, 324, 18, 324, 1, 256, 0, 0, 0, 6, 324);
    jp.j[5] = mk3(Pp2, RWT0, rb0, TAr2, 8, 2, 4, 8, 18, 324, 18, 324, 1, 256, 0, 0, 0, 6, 324);
    conv3_batch<<<dim3(672), 256, 0, stream>>>(jp, out);
  }

  // 9. tower stage 2 (672 blocks)
  {
    Job3Pack jp;
    jp.j[0] = mk3(TAc0, CWT1, cb1, TBc0, 128, 2, 6, 12, 66, 4356, 66, 4356, 1, 256, 0, 0, 0, 7, 396);
    jp.j[1] = mk3(TAr0, RWT1, rb1, TBr0, 128, 2, 6, 12, 66, 4356, 66, 4356, 1, 256, 0, 0, 0, 7, 396);
    jp.j[2] = mk3(TAc1, CWT1, cb1, TBc1, 32, 2, 5, 10, 34, 1156, 34, 1156, 1, 256, 0, 0, 0, 6, 340);
    jp.j[3] = mk3(TAr1, RWT1, rb1, TBr1, 32, 2, 5, 10, 34, 1156, 34, 1156, 1, 256, 0, 0, 0, 6, 340);
    jp.j[4] = mk3(TAc2, CWT1, cb1, TBc2, 8, 2, 4, 8, 18, 324, 18, 324, 1, 256, 0, 0, 0, 6, 324);
    jp.j[5] = mk3(TAr2, RWT1, rb1, TBr2, 8, 2, 4, 8, 18, 324, 18, 324, 1, 256, 0, 0, 0, 6, 324);
    conv3_batch<<<dim3(672), 256, 0, stream>>>(jp, out);
  }

  // 10. tower stage 3 -> detector output (504 blocks)
  {
    Job3Pack jp;
    jp.j[0] = mk3(TBc0, CWT2, cb2, nullptr, 128, 2, 6, 12, 66, 4356, 0, 0, 0, 240, 0, 0, 1, 7, 396);
    jp.j[1] = mk3(TBc1, CWT2, cb2, nullptr, 32, 2, 5, 10, 34, 1156, 0, 0, 0, 240, 4096, 0, 1, 6, 340);
    jp.j[2] = mk3(TBc2, CWT2, cb2, nullptr, 8, 2, 4, 8, 18, 324, 0, 0, 0, 240, 5120, 0, 1, 6, 324);
    jp.j[3] = mk3(TBr0, RWT2, rb2, nullptr, 128, 1, 6, 12, 66, 4356, 0, 0, 0, 12, 0, 240, 1, 7, 396);
    jp.j[4] = mk3(TBr1, RWT2, rb2, nullptr, 32, 1, 5, 10, 34, 1156, 0, 0, 0, 12, 4096, 240, 1, 6, 340);
    jp.j[5] = mk3(TBr2, RWT2, rb2, nullptr, 8, 1, 4, 8, 18, 324, 0, 0, 0, 12, 5120, 240, 1, 6, 324);
    conv3_batch<<<dim3(504), 256, 0, stream>>>(jp, out);
  }

  // 11. anchors
  anchors_k<<<dim3(63), 256, 0, stream>>>(out + 10838016);
}